// Round 5
// baseline (64.088 us; speedup 1.0000x reference)
//
#include <hip/hip_runtime.h>
#include <hip/hip_fp16.h>

typedef _Float16 f16x2 __attribute__((ext_vector_type(2)));
typedef _Float16 f16x8 __attribute__((ext_vector_type(8)));
typedef float    f32x4 __attribute__((ext_vector_type(4)));

#define M_DIM   32
#define K_DIM   8192
#define N_DIM   28672
#define KWORDS  1024           // K/8 packed words per weight row
#define NKB     128            // K/64 scale blocks per row
#define NBLK_N  448            // N/64 n-blocks
#define OUT_ELEMS (M_DIM * N_DIM)

// ---- atomic-fallback init: out[m,n] = bias[n] ----
__global__ __launch_bounds__(256) void wql_init(const float* __restrict__ bias,
                                                float* __restrict__ out) {
    int n = blockIdx.x * 256 + threadIdx.x;
    int m = blockIdx.y;
    out[(size_t)m * N_DIM + n] = bias[n];
}

__device__ __forceinline__ unsigned pkrtz(float a, float b) {
    return __builtin_bit_cast(unsigned, __builtin_amdgcn_cvt_pkrtz(a, b));
}

// 8 nibbles -> 8 dequantized fp16. Pair p = nibbles (p,p+4); 0x6400|q = 1024+q
// exact; cpk = -(1024+8+zq) exact; (f+cpk) is an exact small integer in fp16,
// then one rounding on *spk. k-perm (0,4),(1,5),(2,6),(3,7) matches x staging.
__device__ __forceinline__ f16x8 dq_word(unsigned W, f16x2 spk, f16x2 cpk) {
    union { f16x2 h[4]; f16x8 v; } r;
#pragma unroll
    for (int p = 0; p < 4; ++p) {
        unsigned raw = ((W >> (4 * p)) & 0x000F000Fu) | 0x64006400u;
        f16x2 f = __builtin_bit_cast(f16x2, raw);
        r.h[p] = (f + cpk) * spk;
    }
    return r.v;
}

// 256 thr / 4 waves, n-tile 64 (16 n per wave), all of M=32, KCHUNK = NSB*128.
// launch_bounds(256,2): <=2 blocks/CU (LDS-capped anyway) but ~256 VGPR/wave
// available, so the full hoist (qw -> scales -> zeros -> x) SURVIVES regalloc
// (R4's (512,4) capped VGPR at 64 and the compiler sank all hoisted loads).
// One barrier, unrolled barrier-free compute, partials to ws (no atomics).
template <int NSB, bool ATOMIC>
__global__ __launch_bounds__(256, 2) void wql_main(
    const float* __restrict__ x, const unsigned* __restrict__ qw,
    const float* __restrict__ scales, const unsigned* __restrict__ qzeros,
    float* __restrict__ outp)
{
    // [NSB sections][32 m][16 slots] of uint4; slot = word ^ (m&15)
    // (R1-measured conflict-free pattern).
    __shared__ uint4 xs[NSB * 512];

    const int tid  = threadIdx.x;
    const int bid  = blockIdx.x;
    const int nblk = bid % NBLK_N;
    const int ks   = bid / NBLK_N;
    const int n0   = nblk * 64;
    const int k0   = ks * (NSB * 128);

    const int wv   = tid >> 6;          // 0..3
    const int lane = tid & 63;
    const int g    = (lane >> 4) & 3;
    const int lr   = lane & 15;
    const int gh   = g >> 1;
    const int n_row = n0 + wv * 16 + lr;

    // ---- hoisted qweight stream: lane g owns uint4 (words 4g..4g+3) per section
    uint4 wq[NSB];
    const uint4* qp = (const uint4*)(qw + (size_t)n_row * KWORDS + (k0 >> 3));
#pragma unroll
    for (int s = 0; s < NSB; ++s) wq[s] = qp[4 * s + g];

    // ---- scales: NSB*2 floats per row, as f32x4 vectors
    f32x4 s4[NSB / 2];
    const f32x4* srow = (const f32x4*)(scales + (size_t)n_row * NKB + (k0 >> 6));
#pragma unroll
    for (int i = 0; i < NSB / 2; ++i) s4[i] = srow[i];

    // ---- zeros: NSB*2 nibbles per row; word offset = (k0/64)/8 = k0>>9
    unsigned zwv[NSB / 4];
    const unsigned* zrow = qzeros + (size_t)n_row * (NKB / 8) + (k0 >> 9);
    {
        uint2 z = *(const uint2*)zrow; zwv[0] = z.x;
        if constexpr (NSB >= 8) zwv[1] = z.y;
    }

    // ---- stage x -> LDS fp16 (pair-permuted). Thread covers row mt,
    // slots sl0,sl0+1 per section: 16 consecutive f32 = 4 coalesced float4.
    {
        const int mt  = tid >> 3;       // 0..31
        const int sl0 = (tid & 7) * 2;  // 0,2,..14
        const float* xp = x + (size_t)mt * K_DIM + k0 + sl0 * 8;
        const int xbase = mt * 16;
        const int sw0 = sl0 ^ (mt & 15);
        const int sw1 = (sl0 + 1) ^ (mt & 15);
#pragma unroll
        for (int sec = 0; sec < NSB; ++sec) {
            const float4* p = (const float4*)(xp + sec * 128);
            float4 f0 = p[0], f1 = p[1], f2 = p[2], f3 = p[3];
            uint4 v0 = { pkrtz(f0.x, f1.x), pkrtz(f0.y, f1.y),
                         pkrtz(f0.z, f1.z), pkrtz(f0.w, f1.w) };
            uint4 v1 = { pkrtz(f2.x, f3.x), pkrtz(f2.y, f3.y),
                         pkrtz(f2.z, f3.z), pkrtz(f2.w, f3.w) };
            xs[sec * 512 + xbase + sw0] = v0;
            xs[sec * 512 + xbase + sw1] = v1;
        }
    }
    __syncthreads();

    f32x4 acc0 = {0.f, 0.f, 0.f, 0.f};
    f32x4 acc1 = {0.f, 0.f, 0.f, 0.f};

#pragma unroll
    for (int sb = 0; sb < NSB; ++sb) {
        // scale block within chunk = 2*sb + gh; nibble (2sb+gh)&7 of word (2sb)>>3
        const int zq = (zwv[(2 * sb) >> 3] >> (4 * ((2 * sb + gh) & 7))) & 0xF;
        const float sf = gh ? s4[sb >> 1][(sb & 1) * 2 + 1]
                            : s4[sb >> 1][(sb & 1) * 2];
        const _Float16 sh = (_Float16)sf;
        const _Float16 ch = (_Float16)(-(float)(1032 + zq));
        const f16x2 spk = { sh, sh };
        const f16x2 cpk = { ch, ch };
        const unsigned wa[4] = { wq[sb].x, wq[sb].y, wq[sb].z, wq[sb].w };
#pragma unroll
        for (int j = 0; j < 4; ++j) {
            f16x8 a = dq_word(wa[j], spk, cpk);
            const int w = 4 * g + j;
            f16x8 b0 = __builtin_bit_cast(f16x8, xs[sb * 512 + lr * 16        + (w ^ lr)]);
            f16x8 b1 = __builtin_bit_cast(f16x8, xs[sb * 512 + (lr + 16) * 16 + (w ^ lr)]);
            acc0 = __builtin_amdgcn_mfma_f32_16x16x32_f16(a, b0, acc0, 0, 0, 0);
            acc1 = __builtin_amdgcn_mfma_f32_16x16x32_f16(a, b1, acc1, 0, 0, 0);
        }
    }

    // C/D: col(m) = lane&15, n-within-16 = 4*(lane>>4)+reg
    const size_t obase = (size_t)lr * N_DIM + n0 + wv * 16 + 4 * g;
    if constexpr (ATOMIC) {
#pragma unroll
        for (int r = 0; r < 4; ++r) {
            atomicAdd(outp + obase + r, acc0[r]);
            atomicAdd(outp + obase + (size_t)16 * N_DIM + r, acc1[r]);
        }
    } else {
        float* dst = outp + (size_t)ks * OUT_ELEMS;
        *(f32x4*)(dst + obase) = acc0;
        *(f32x4*)(dst + obase + (size_t)16 * N_DIM) = acc1;
    }
}

// out = bias + sum of 8 split partials (ws path; partials are L3-resident)
__global__ __launch_bounds__(256) void wql_reduce(const float* __restrict__ ws,
                                                  const float* __restrict__ bias,
                                                  float* __restrict__ out) {
    const int i4 = (blockIdx.x * 256 + threadIdx.x) * 4;
    const int n  = i4 % N_DIM;
    f32x4 acc = *(const f32x4*)(bias + n);
#pragma unroll
    for (int s = 0; s < 8; ++s)
        acc += *(const f32x4*)(ws + (size_t)s * OUT_ELEMS + i4);
    *(f32x4*)(out + i4) = acc;
}

extern "C" void kernel_launch(void* const* d_in, const int* in_sizes, int n_in,
                              void* d_out, int out_size, void* d_ws, size_t ws_size,
                              hipStream_t stream) {
    const float*    x      = (const float*)d_in[0];
    const unsigned* qwght  = (const unsigned*)d_in[1];
    const float*    scales = (const float*)d_in[2];
    const unsigned* qzeros = (const unsigned*)d_in[3];
    const float*    bias   = (const float*)d_in[4];
    float* out = (float*)d_out;

    const size_t need = (size_t)8 * OUT_ELEMS * sizeof(float);  // 29.4 MB
    if (ws_size >= need) {
        // 8-way K split, partials -> ws (no atomics), then reduce
        wql_main<8, false><<<dim3(NBLK_N * 8), 256, 0, stream>>>(
            x, qwght, scales, qzeros, (float*)d_ws);
        wql_reduce<<<dim3(OUT_ELEMS / 1024), 256, 0, stream>>>(
            (const float*)d_ws, bias, out);
    } else {
        // fallback: 8-way split with atomics onto bias-initialized out
        wql_init<<<dim3(N_DIM / 256, M_DIM), 256, 0, stream>>>(bias, out);
        wql_main<8, true><<<dim3(NBLK_N * 8), 256, 0, stream>>>(
            x, qwght, scales, qzeros, out);
    }
}